// Round 1
// baseline (277.180 us; speedup 1.0000x reference)
//
#include <hip/hip_runtime.h>
#include <cstdint>
#include <math.h>

#define K_TOK 2048
#define TPL   32      // tokens per lane (K_TOK / 64)
#define BLK   512
#define WPB   8       // waves (=rows) per block

// monotonic float->uint key (total order; ascending key == ascending float)
__device__ __forceinline__ uint32_t f2key(float f) {
    uint32_t u = __float_as_uint(f);
    return u ^ ((uint32_t)(((int32_t)u) >> 31) | 0x80000000u);
}
__device__ __forceinline__ float key2f(uint32_t k) {
    uint32_t m = ((uint32_t)((~(int32_t)k) >> 31)) | 0x80000000u;
    return __uint_as_float(k ^ m);
}

// Precompute per-token: B4[k] = flat b[2..5], SB[k] = sum(b*b) in reference order.
__global__ void prep_kernel(const float* __restrict__ mpt,
                            float4* __restrict__ b4out, float* __restrict__ sbout) {
    #pragma clang fp contract(off)
    int k = blockIdx.x * blockDim.x + threadIdx.x;
    if (k >= K_TOK) return;
    float b0 = mpt[k*6+0], b1 = mpt[k*6+1], b2 = mpt[k*6+2];
    float b3 = mpt[k*6+3], b4 = mpt[k*6+4], b5 = mpt[k*6+5];
    float q0 = b0*b0, q1 = b1*b1, q2 = b2*b2, q3 = b3*b3, q4 = b4*b4, q5 = b5*b5;
    float s = ((((q0+q1)+q2)+q3)+q4)+q5;   // sequential, no fma (contract off)
    b4out[k] = make_float4(b2, b3, b4, b5);
    sbout[k] = s;
}

__global__ __launch_bounds__(BLK) void topk_kernel(
        const float* __restrict__ traj_pos, const float* __restrict__ traj_theta,
        const float4* __restrict__ b4g, const float* __restrict__ sbg,
        const float* __restrict__ token_src, const float* __restrict__ gumbel,
        float* __restrict__ out, int Nrows) {
    #pragma clang fp contract(off)
    __shared__ float4   sB4[K_TOK];
    __shared__ float    sSB[K_TOK];
    __shared__ uint32_t sCK[WPB][64];
    __shared__ uint16_t sCI[WPB][64];
    __shared__ uint32_t sSK[WPB][32];
    __shared__ uint16_t sSI[WPB][32];

    const int tid = threadIdx.x;
    for (int t = tid; t < K_TOK; t += BLK) { sB4[t] = b4g[t]; sSB[t] = sbg[t]; }
    __syncthreads();

    const int wv   = tid >> 6;
    const int lane = tid & 63;
    const int n    = blockIdx.x * WPB + wv;
    if (n >= Nrows) return;

    // ---- per-row local frame (match reference op-for-op, f32, no contraction)
    const float* tp = traj_pos + (size_t)n * 6;
    float p0x = tp[0], p0y = tp[1];
    float dx1 = tp[2] - p0x, dy1 = tp[3] - p0y;
    float dx2 = tp[4] - p0x, dy2 = tp[5] - p0y;
    float th = traj_theta[n];
    float c = (float)cos((double)th);   // correctly-rounded f32 trig
    float s = (float)sin((double)th);
    float ns = -s;
    float a2 = c*dx1 + s*dy1;   // lx1: mul, mul, add (separate roundings)
    float a3 = ns*dx1 + c*dy1;  // ly1
    float a4 = c*dx2 + s*dy2;   // lx2
    float a5 = ns*dx2 + c*dy2;  // ly2
    float q2 = a2*a2, q3 = a3*a3, q4 = a4*a4, q5 = a5*a5;
    float sa = ((q2 + q3) + q4) + q5;   // leading exact zeros of a drop out

    // ---- distances for this lane's 32 tokens (kept in registers as keys)
    uint32_t kk[TPL];
    #pragma unroll
    for (int j = 0; j < TPL; ++j) {
        int t = j * 64 + lane;
        float4 b = sB4[t];
        float sbv = sSB[t];
        float d0 = a2 * b.x;            // == fma(a2,b2,0): single rounding
        d0 = fmaf(a3, b.y, d0);         // ascending-k fma chain (BLAS-style)
        d0 = fmaf(a4, b.z, d0);
        d0 = fmaf(a5, b.w, d0);
        float t2  = 2.0f * d0;          // exact
        float dist = (sa + sbv) - t2;   // reference association order
        kk[j] = f2key(dist);
    }

    // ---- binary search (MSB->LSB) for threshold key A with count(key<=A) in [32,64]
    uint32_t A = 0;
    int cnt = 0;
    bool found = false;
    for (int b = 31; b >= 0; --b) {
        uint32_t T = A | ((1u << b) - 1u);
        int cc = 0;
        #pragma unroll
        for (int j = 0; j < TPL; ++j) cc += (kk[j] <= T) ? 1 : 0;
        for (int m = 1; m < 64; m <<= 1) cc += __shfl_xor(cc, m, 64);
        if (cc >= 32) {
            if (cc <= 64) { A = T; cnt = cc; found = true; break; }
            // else keep bit b = 0, narrow further
        } else {
            A |= (1u << b);
        }
    }
    if (!found) {  // A is now the exact 32nd-smallest key; recount
        int cc = 0;
        #pragma unroll
        for (int j = 0; j < TPL; ++j) cc += (kk[j] <= A) ? 1 : 0;
        for (int m = 1; m < 64; m <<= 1) cc += __shfl_xor(cc, m, 64);
        cnt = cc;
    }
    int cnt_cap = cnt > 64 ? 64 : cnt;

    // ---- ordered-compaction of candidates (key<=A) into per-wave LDS buffer
    int base = 0;
    #pragma unroll
    for (int j = 0; j < TPL; ++j) {
        bool p = (kk[j] <= A);
        uint64_t mask = __ballot(p);
        if (p) {
            int pos = base + (int)__popcll(mask & ((1ull << lane) - 1ull));
            if (pos < 64) {
                sCK[wv][pos] = kk[j];
                sCI[wv][pos] = (uint16_t)(j * 64 + lane);
            }
        }
        base += (int)__popcll(mask);
    }

    // ---- exact rank-sort of candidates by (dist, idx)  -> slots 0..31
    bool valid = (lane < cnt_cap);
    uint32_t myk = valid ? sCK[wv][lane] : 0xFFFFFFFFu;
    uint32_t myi = valid ? (uint32_t)sCI[wv][lane] : 0xFFFFu;
    uint64_t key64 = ((uint64_t)myk << 16) | (uint64_t)myi;
    int rank = 0;
    for (int l = 0; l < cnt_cap; ++l) {
        uint64_t o = __shfl(key64, l, 64);
        rank += (o < key64) ? 1 : 0;
    }
    if (valid && rank < 32) {
        sSK[wv][rank] = myk;
        sSI[wv][rank] = (uint16_t)myi;
    }

    // ---- gumbel-argmax over the 32 sorted slots (tie -> lower slot)
    const float C1F = (float)(1.0 - 2.0 * 1e-7);
    float score;
    int slot = lane;
    if (lane < 32) {
        float dist = key2f(sSK[wv][lane]);
        float neg   = -dist;
        float logit = (-1e-6f) + neg;           // /1.0 exact, omitted
        float u = gumbel[(size_t)n * 32 + lane];
        float t = u * C1F;
        t = t + 1e-7f;
        float li = (float)log((double)t);       // correctly-rounded f32 log
        float ni = -li;
        float lo = (float)log((double)ni);
        float g  = -lo;
        score = logit + g;
    } else {
        score = -INFINITY;
    }
    for (int m = 1; m < 64; m <<= 1) {
        float so = __shfl_xor(score, m, 64);
        int   sl = __shfl_xor(slot,  m, 64);
        if (so > score || (so == score && sl < slot)) { score = so; slot = sl; }
    }
    int tw = (int)sSI[wv][slot];   // winning token (slot uniform across wave)

    if (lane < 22) out[(size_t)n * 22 + lane] = token_src[(size_t)tw * 22 + lane];
}

extern "C" void kernel_launch(void* const* d_in, const int* in_sizes, int n_in,
                              void* d_out, int out_size, void* d_ws, size_t ws_size,
                              hipStream_t stream) {
    const float* traj_pos   = (const float*)d_in[0];
    const float* traj_theta = (const float*)d_in[1];
    const float* mpt        = (const float*)d_in[2];
    const float* token_src  = (const float*)d_in[3];
    const float* gumbel     = (const float*)d_in[4];
    float* out = (float*)d_out;

    int N = in_sizes[0] / 6;

    float4* b4 = (float4*)d_ws;
    float*  sb = (float*)((char*)d_ws + K_TOK * sizeof(float4));

    hipLaunchKernelGGL(prep_kernel, dim3(K_TOK / 256), dim3(256), 0, stream,
                       mpt, b4, sb);

    int blocks = (N + WPB - 1) / WPB;
    hipLaunchKernelGGL(topk_kernel, dim3(blocks), dim3(BLK), 0, stream,
                       traj_pos, traj_theta, b4, sb, token_src, gumbel, out, N);
}